// Round 14
// baseline (145.141 us; speedup 1.0000x reference)
//
#include <hip/hip_runtime.h>

// Bilinear backward warp, NCHW f32 — pipelined LDS channel loop, small blocks.
// Block = 32x16 tile, 512 threads (1 px/thread), CGB=2 channels/phase,
// ping-pong LDS (2 x 2 x 40x24 planes = 15.4 KB) -> 4 blocks/CU: four
// INDEPENDENT barrier domains per CU so one block's barrier-convergence
// dead-time is covered by the other three (R12 showed 2 domains leave
// ~7K cycles/phase idle; depth-2 prefetch proved it's not DMA latency).
// Zero duplicate staging DMAs (NSTG=480 <= 512 threads; R11/12 wasted 42%).
// Staging via global_load_lds width-16, lane-consecutive slots per wave
// (wave-uniform base + lane*16 — R10 lesson). Counted s_waitcnt vmcnt(2)
// + raw s_barrier per phase; output stores stay in flight.

#define TSX 32
#define TSY 16
#define RAD 4
#define LW  (TSX + 2*RAD)     // 40
#define LH  (TSY + 2*RAD)     // 24
#define GPR (LW/4)            // 10 float4 groups per row
#define PLANE (LW*LH)         // 960 floats = 3840 B
#define NV  (LH*GPR)          // 240 groups per plane
#define CGB 2                 // channels per buffer
#define BUFSZ (CGB*PLANE)     // 1920 floats
#define NSTG (CGB*NV)         // 480 DMA slots per phase
#define NTHREADS 512

static_assert(NSTG <= NTHREADS, "one DMA slot per thread, no wrap");

#define GLOAD_LDS16(g, l)                                                  \
    __builtin_amdgcn_global_load_lds(                                      \
        (const __attribute__((address_space(1))) void*)(g),                \
        (__attribute__((address_space(3))) void*)(l), 16, 0, 0)

__global__ __launch_bounds__(NTHREADS, 8) void warp_small(
    const float* __restrict__ img,
    const float* __restrict__ flow,
    const int* __restrict__ Hp,
    const int* __restrict__ Wp,
    float* __restrict__ out,
    int HW, int C)
{
    __shared__ __align__(16) float lds[2 * BUFSZ];   // 15360 B

    const int W = *Wp;
    const int H = *Hp;
    const int tilesX = (W + TSX - 1) / TSX;
    const int tilesY = (H + TSY - 1) / TSY;
    const int ntiles = tilesX * tilesY;
    const int bid = blockIdx.x;
    if (bid >= ntiles) return;

    // bijective XCD band swizzle
    const int q = ntiles >> 3, r = ntiles & 7;
    const int xcd = bid & 7, sub = bid >> 3;
    const int t = (xcd < r ? xcd*(q+1) : r*(q+1) + (xcd-r)*q) + sub;

    const int tileY = t / tilesX;
    const int tileX = t - tileY * tilesX;
    const int gx0 = tileX * TSX - RAD;   // ≡ 0 (mod 4)
    const int gy0 = tileY * TSY - RAD;

    const int tid = threadIdx.x;
    const int lx  = tid & (TSX - 1);     // 0..31
    const int row = tid >> 5;            // 0..15
    const int gx  = tileX * TSX + lx;
    const int gy  = tileY * TSY + row;

    const float Wm1 = (float)(W - 1);
    const float Hm1 = (float)(H - 1);

    // ---- per-pixel precompute (1 px/thread, once per tile) ----
    float a0 = 0.f, a1 = 0.f, a2 = 0.f, a3 = 0.f;
    int enc = -2, pix = 0;
    if (gx < W && gy < H) {
        pix = gy * W + gx;
        const float u = flow[pix];
        const float v = flow[HW + pix];

        // normalize/denormalize round-trip omitted (identity, +-1 ulp)
        const float x = (float)gx + u;
        const float y = (float)gy + v;
        const float x0 = floorf(x), x1 = x0 + 1.0f;
        const float y0 = floorf(y), y1 = y0 + 1.0f;

        const int x0c = (int)fminf(fmaxf(x0, 0.0f), Wm1);
        const int x1c = (int)fminf(fmaxf(x1, 0.0f), Wm1);
        const int y0c = (int)fminf(fmaxf(y0, 0.0f), Hm1);
        const int y1c = (int)fminf(fmaxf(y1, 0.0f), Hm1);

        const float wa = (x1 - x) * (y1 - y);
        const float wb = (x1 - x) * (y - y0);
        const float wc = (x - x0) * (y1 - y);
        const float wd = (x - x0) * (y - y0);

        const int pbx = min(x0c, W - 2);
        const int pby = min(y0c, H - 2);

        const float wlt = (x0c == pbx ? wa : 0.f) + (x1c == pbx ? wc : 0.f);
        const float wht = (x0c != pbx ? wa : 0.f) + (x1c != pbx ? wc : 0.f);
        const float wlb = (x0c == pbx ? wb : 0.f) + (x1c == pbx ? wd : 0.f);
        const float whb = (x0c != pbx ? wb : 0.f) + (x1c != pbx ? wd : 0.f);
        const bool t0 = (y0c == pby), t1 = (y1c == pby);
        a0 = (t0 ? wlt : 0.f) + (t1 ? wlb : 0.f);
        a1 = (t0 ? wht : 0.f) + (t1 ? whb : 0.f);
        a2 = (t0 ? 0.f : wlt) + (t1 ? 0.f : wlb);
        a3 = (t0 ? 0.f : wht) + (t1 ? 0.f : whb);

        const int lxp = pbx - gx0;
        const int lyb = pby - gy0;
        enc = (lxp >= 0 && lxp <= LW-2 && lyb >= 0 && lyb <= LH-2)
            ? (lyb * LW + lxp) : -1;
    }

    float* optr = out + pix;

    // ---- staging descriptor (1 slot/thread; lane-consecutive) ----
    int spix = 0, chrel = 0, dst4 = 0;
    const bool stg = (tid < NSTG);
    if (stg) {
        const int ch  = tid / NV;
        const int rem = tid - ch * NV;
        const int rr  = rem / GPR;
        const int g   = rem - rr * GPR;
        const int yy  = min(max(gy0 + rr, 0), H - 1);
        const int xs  = min(max(gx0 + 4*g, 0), W - 4);  // group fully in/out
        chrel = ch;
        spix  = yy * W + xs;
        dst4  = tid * 4;
    }

    const int nph = (C + CGB - 1) / CGB;
    const bool fast = ((W & 3) == 0) && ((tileX+1)*TSX <= W)
                   && ((tileY+1)*TSY <= H);

    // gather one phase (2 channels) from `cur`
    auto gather2 = [&](const float* cur, int c0) {
        if (enc == -2) return;
        if (__builtin_expect(enc >= 0, 1)) {
            const float* b0 = cur + enc;
            optr[0] = a0*b0[0] + a1*b0[1] + a2*b0[LW] + a3*b0[LW+1];
            if (c0 + 1 < C)
                optr[HW] = a0*b0[PLANE]    + a1*b0[PLANE+1]
                         + a2*b0[PLANE+LW] + a3*b0[PLANE+LW+1];
        } else {
            // rare out-of-halo flow (|flow|>~4): recompute + global gather
            const float u = flow[pix];
            const float v = flow[HW + pix];
            const float x = (float)gx + u;
            const float y = (float)gy + v;
            const float x0 = floorf(x), y0f = floorf(y);
            const int x0c = (int)fminf(fmaxf(x0, 0.f), Wm1);
            const int x1c = (int)fminf(fmaxf(x0 + 1.f, 0.f), Wm1);
            const int y0c = (int)fminf(fmaxf(y0f, 0.f), Hm1);
            const int y1c = (int)fminf(fmaxf(y0f + 1.f, 0.f), Hm1);
            const float wa = (x0 + 1.f - x) * (y0f + 1.f - y);
            const float wb = (x0 + 1.f - x) * (y - y0f);
            const float wc = (x - x0) * (y0f + 1.f - y);
            const float wd = (x - x0) * (y - y0f);
            for (int c = 0; c < CGB && c0 + c < C; ++c) {
                const float* ic = img + (size_t)(c0 + c) * HW;
                optr[(size_t)c * HW] =
                      wa * ic[(size_t)y0c*W + x0c] + wb * ic[(size_t)y1c*W + x0c]
                    + wc * ic[(size_t)y0c*W + x1c] + wd * ic[(size_t)y1c*W + x1c];
            }
        }
    };

    if (fast) {
        float* cur = &lds[0];
        float* nxt = &lds[BUFSZ];

        // prologue: stage phase 0
        if (stg) {
            const int chc = min(chrel, C - 1);
            GLOAD_LDS16(img + (size_t)chc * HW + spix, cur + dst4);
        }
        asm volatile("s_waitcnt vmcnt(0)" ::: "memory");
        __builtin_amdgcn_s_barrier();
        __builtin_amdgcn_sched_barrier(0);

        for (int p = 0; p < nph; ++p) {
            const int c0 = p * CGB;

            if (p + 1 < nph && stg) {     // issue next-phase DMA first
                const int chc = min(c0 + CGB + chrel, C - 1);
                GLOAD_LDS16(img + (size_t)chc * HW + spix, nxt + dst4);
            }
            __builtin_amdgcn_sched_barrier(0);   // pin: DMA before stores

            gather2(cur, c0);                    // 2 stores per thread

            __builtin_amdgcn_sched_barrier(0);   // pin: stores before wait

            if (p + 1 < nph) {
                // ops issued after D(p+1): this phase's 2 stores ->
                // vmcnt(2) => D(p+1) retired; stores stay in flight.
                asm volatile("s_waitcnt vmcnt(2)" ::: "memory");
                __builtin_amdgcn_sched_barrier(0);
                __builtin_amdgcn_s_barrier();
                __builtin_amdgcn_sched_barrier(0);
            }
            float* tmp = cur; cur = nxt; nxt = tmp;
            optr += (size_t)CGB * HW;
        }
    } else {
        // generic slow path (partial tiles / W%4!=0): scalar stage + full syncs
        for (int p = 0; p < nph; ++p) {
            const int c0 = p * CGB;
            __syncthreads();
            for (int i = tid; i < BUFSZ; i += NTHREADS) {
                const int ch  = i / PLANE;
                const int rem = i - ch * PLANE;
                const int rr  = rem / LW;
                const int cc  = rem - rr * LW;
                const int yy  = min(max(gy0 + rr, 0), H - 1);
                const int xx  = min(max(gx0 + cc, 0), W - 1);
                const int chc = min(c0 + ch, C - 1);
                lds[i] = img[(size_t)chc * HW + (size_t)yy * W + xx];
            }
            __syncthreads();
            gather2(&lds[0], c0);
            optr += (size_t)CGB * HW;
        }
    }
}

extern "C" void kernel_launch(void* const* d_in, const int* in_sizes, int n_in,
                              void* d_out, int out_size, void* d_ws, size_t ws_size,
                              hipStream_t stream) {
    const float* img  = (const float*)d_in[0];
    const float* flow = (const float*)d_in[1];
    const int*   Hp   = (const int*)d_in[2];
    const int*   Wp   = (const int*)d_in[3];
    float* out = (float*)d_out;

    const int HW = in_sizes[1] / 2;    // flow is (1,2,H,W)
    const int C  = in_sizes[0] / HW;   // img is (1,C,H,W)

    // host doesn't know W,H (device scalars): launch with tile slack,
    // excess blocks exit on the in-kernel ntiles guard.
    const int grid = (HW + TSX * TSY - 1) / (TSX * TSY) + 64;
    warp_small<<<grid, NTHREADS, 0, stream>>>(img, flow, Hp, Wp, out, HW, C);
}